// Round 15
// baseline (109.828 us; speedup 1.0000x reference)
//
#include <hip/hip_runtime.h>

#define NS 128
#define NRAYS 8192

typedef unsigned short u16;
typedef unsigned int   u32;
typedef unsigned short u16x8 __attribute__((ext_vector_type(8)));
typedef __bf16 b16x8 __attribute__((ext_vector_type(8)));
typedef float f32x4 __attribute__((ext_vector_type(4)));
typedef _Float16 h16x2 __attribute__((ext_vector_type(2)));
typedef unsigned int u32x4 __attribute__((ext_vector_type(4)));
typedef unsigned int u32x2 __attribute__((ext_vector_type(2)));
typedef float f32x2u __attribute__((ext_vector_type(2), aligned(4)));

__device__ __forceinline__ float clampf(float x, float lo, float hi) {
    return fminf(fmaxf(x, lo), hi);
}

__device__ __forceinline__ u16 f2bf(float f) {
    return __builtin_bit_cast(u16, (__bf16)f);
}

// pack two f32 -> bf16 pair in one u32 (lo in bits 0-15)
__device__ __forceinline__ u32 pk2bf(float lo, float hi) {
    return (u32)f2bf(lo) | ((u32)f2bf(hi) << 16);
}

__device__ __forceinline__ u32 pkh(float a, float b) {
    h16x2 v; v[0] = (_Float16)a; v[1] = (_Float16)b;
    return __builtin_bit_cast(u32, v);
}
__device__ __forceinline__ float2 uph(u32 u) {
    h16x2 v = __builtin_bit_cast(h16x2, u);
    return make_float2((float)v[0], (float)v[1]);
}

__device__ __forceinline__ f32x4 mfma_bf16(u16x8 a, u16x8 b, f32x4 c) {
    return __builtin_amdgcn_mfma_f32_16x16x32_bf16(
        __builtin_bit_cast(b16x8, a), __builtin_bit_cast(b16x8, b), c, 0, 0, 0);
}

// swizzled u16-index into a [16][64] tile stored [sample][dim]
#define TSW(n, k) ((((n) * 64) + (k)) ^ (((n) & 7) << 3))

__device__ __forceinline__ void plane_interp(const float* __restrict__ g,
                                             float ca, float cb, float o[3]) {
    float pa = clampf((ca + 1.f) * (0.5f * 127.f), 0.f, 127.f);
    float pb = clampf((cb + 1.f) * (0.5f * 127.f), 0.f, 127.f);
    int la = (int)pa; if (la > 126) la = 126;
    int lb = (int)pb; if (lb > 126) lb = 126;
    float fa = pa - (float)la, fb = pb - (float)lb;
    const float* p = g + la * 128 + lb;
#pragma unroll
    for (int c = 0; c < 3; ++c) {
        const float* q = p + c * 16384;
        f32x2u q0 = *(const f32x2u*)q;
        f32x2u q1 = *(const f32x2u*)(q + 128);
        float top = fmaf(q0[1] - q0[0], fb, q0[0]);
        float bot = fmaf(q1[1] - q1[0], fb, q1[0]);
        o[c] = fmaf(bot - top, fa, top);
    }
}

// ---- prep: pack weight A-fragments (bf16, per-lane layout) into workspace ----
// AWc1' rows: [0]=0, [1..15]=wc1 so-rows, [16..18]=wc1 dir-rows, [19]=bc1 (bias
// row, pairs with cin' row19 == 1.0), [20..31]=0.
// layout (u16x8 units): [0,256) AW1 (nb*64+lane), [256,512) AWc1',
//                       [512,640) AW2 (ks*64+lane), [640,768) AWc2
__global__ __launch_bounds__(256)
void prep_weights(const float* __restrict__ w1, const float* __restrict__ wc1,
                  const float* __restrict__ w2, const float* __restrict__ wc2,
                  const float* __restrict__ bc1,
                  u16* __restrict__ wsb)
{
    int idx = blockIdx.x * 256 + threadIdx.x;   // 0..6143
    if (idx >= 6144) return;
    int lane = (idx >> 3) & 63;
    int j = idx & 7;
    int c16 = lane & 15, kg = lane >> 4;
    float v;
    if (idx < 2048) {                       // AW1
        int nb = idx >> 9;
        int k = kg * 8 + j;
        v = w1[k * 64 + nb * 16 + c16];
    } else if (idx < 4096) {                // AWc1' (permuted rows + bias row)
        int nb = (idx - 2048) >> 9;
        int k = kg * 8 + j;
        if (k == 0)       v = 0.f;
        else if (k < 16)  v = wc1[(k + 2) * 64 + nb * 16 + c16];
        else if (k < 19)  v = wc1[(k - 16) * 64 + nb * 16 + c16];
        else if (k == 19) v = bc1[nb * 16 + c16];
        else              v = 0.f;
    } else if (idx < 5120) {                // AW2
        int ks = (idx - 4096) >> 9;
        int k = ks * 32 + kg * 8 + j;
        v = w2[k * 16 + c16];
    } else {                                // AWc2 (M padded 3->16)
        int ks = (idx - 5120) >> 9;
        int k = ks * 32 + kg * 8 + j;
        v = (c16 < 3) ? wc2[k * 3 + c16] : 0.f;
    }
    wsb[idx] = f2bf(v);
}

// block = 4 rays, 4 waves, 1 wave = 1 ray, 8 chunks of 16 samples per wave.
// AW1/AWc1 in block-shared LDS; AW2/AWc2 in VGPRs. GEMM1/GEMM3 accumulators
// computed in TWO HALVES (peak live acc 8 f32x4 instead of 16) so the unified
// VGPR+AGPR footprint fits the 128-reg cap from __launch_bounds__(256,4)
// (4 blocks/CU target; r6's spill came from a ~150-reg structure, this is ~120).
__global__ __launch_bounds__(256, 4)
void nerf_mfma(const float* __restrict__ rays_o,
               const float* __restrict__ rays_d,
               const float* __restrict__ bg_color,
               const float* __restrict__ plane01,
               const float* __restrict__ plane02,
               const float* __restrict__ plane12,
               const float* __restrict__ features,
               const float* __restrict__ w1, const float* __restrict__ b1,
               const float* __restrict__ w2, const float* __restrict__ b2,
               const float* __restrict__ wc1, const float* __restrict__ bc1,
               const float* __restrict__ wc2, const float* __restrict__ bc2,
               const float* __restrict__ aabb,
               float* __restrict__ out,
               const u16* __restrict__ wsb, int use_ws)
{
    __shared__ __align__(16) u16x8 s_wfrag[512];        // AW1 + AWc1' (8 KB)
    __shared__ __align__(16) float s_bias[96];          // b1[64], b2[16], bc2pad[16]
    __shared__ __align__(16) u32x4 s_cw[4][128];        // trilinear corner weights
    __shared__ u32   s_fb[4][128];                      // cell base BYTE offsets
    __shared__ __align__(16) u16  s_tile[4][16 * 64];   // per-wave transpose tile
    __shared__ float s_tau[4][128];
    __shared__ u32   s_rgbrg[4][128];                   // f16 pair (r,g)
    __shared__ u16   s_rgbb[4][128];                    // f16 b

    const int tid  = threadIdx.x;
    const int wv   = tid >> 6;
    const int lane = tid & 63;
    const int c16  = lane & 15;
    const int kg   = lane >> 4;
    const int ray  = blockIdx.x * 4 + wv;
    const int sA   = c16 + 16 * ((2 * kg) & 3);
    const int sB   = c16 + 16 * ((2 * kg + 1) & 3);

    // ---- stage AW1/AWc1 to LDS; AW2/AWc2 to VGPRs ----
    u16x8 AW2[2], AWc2[2];
    if (use_ws) {
        const u16x8* wf = (const u16x8*)wsb;
#pragma unroll
        for (int i = 0; i < 2; ++i) s_wfrag[tid + 256 * i] = wf[tid + 256 * i];
#pragma unroll
        for (int ks = 0; ks < 2; ++ks) {
            AW2[ks]  = wf[512 + ks * 64 + lane];
            AWc2[ks] = wf[640 + ks * 64 + lane];
        }
    } else {
        if (wv == 0) {
#pragma unroll
            for (int nb = 0; nb < 4; ++nb) {
                u16x8 a, c;
#pragma unroll
                for (int j = 0; j < 8; ++j) {
                    int k = kg * 8 + j;
                    a[j] = f2bf(w1[k * 64 + nb * 16 + c16]);
                    float v;
                    if (k == 0)       v = 0.f;
                    else if (k < 16)  v = wc1[(k + 2) * 64 + nb * 16 + c16];
                    else if (k < 19)  v = wc1[(k - 16) * 64 + nb * 16 + c16];
                    else if (k == 19) v = bc1[nb * 16 + c16];
                    else              v = 0.f;
                    c[j] = f2bf(v);
                }
                s_wfrag[nb * 64 + lane] = a;
                s_wfrag[256 + nb * 64 + lane] = c;
            }
        }
#pragma unroll
        for (int ks = 0; ks < 2; ++ks)
#pragma unroll
            for (int j = 0; j < 8; ++j) {
                int k = ks * 32 + kg * 8 + j;
                AW2[ks][j]  = f2bf(w2[k * 16 + c16]);
                AWc2[ks][j] = f2bf(c16 < 3 ? wc2[k * 3 + c16] : 0.f);
            }
    }
    if (tid < 96) {
        float v;
        if (tid < 64)      v = b1[tid];
        else if (tid < 80) v = b2[tid - 64];
        else               v = (tid - 80 < 3) ? bc2[tid - 80] : 0.f;
        s_bias[tid] = v;
    }

    // ---- per-ray setup ----
    float ox = rays_o[ray * 3 + 0], oy = rays_o[ray * 3 + 1], oz = rays_o[ray * 3 + 2];
    float dx = rays_d[ray * 3 + 0], dy = rays_d[ray * 3 + 1], dz = rays_d[ray * 3 + 2];
    float rn = rsqrtf(dx * dx + dy * dy + dz * dz);
    dx *= rn; dy *= rn; dz *= rn;

    float lo0 = aabb[0], lo1 = aabb[1], lo2 = aabb[2];
    float hi0 = aabb[3], hi1 = aabb[4], hi2 = aabb[5];

    float invx = 1.f / dx, invy = 1.f / dy, invz = 1.f / dz;
    float tx0 = (lo0 - ox) * invx, tx1 = (hi0 - ox) * invx;
    float ty0 = (lo1 - oy) * invy, ty1 = (hi1 - oy) * invy;
    float tz0 = (lo2 - oz) * invz, tz1 = (hi2 - oz) * invz;
    float tnear = fmaxf(fmaxf(fminf(tx0, tx1), fminf(ty0, ty1)), fminf(tz0, tz1));
    tnear = fmaxf(tnear, 0.f);
    float tfar = fminf(fminf(fmaxf(tx0, tx1), fmaxf(ty0, ty1)), fmaxf(tz0, tz1));
    tfar = fmaxf(tfar, tnear);
    float delta = (tfar - tnear) * (1.f / (float)NS);

    // dir constants for cin' rows 16..18 + bias row 19 (kg==2 k-slice)
    const u32 dir01 = pk2bf(dx, dy);
    const u32 dir2b = pk2bf(dz, 1.0f);

    // ---- coordinate phase: this wave, 2 samples per lane ----
#pragma unroll
    for (int i = 0; i < 2; ++i) {
        int s = i * 64 + lane;
        float t = tnear + delta * ((float)s + 0.5f);
        float px = ox + dx * t, py = oy + dy * t, pz = oz + dz * t;
        px = (px - lo0) * (2.f / (hi0 - lo0)) - 1.f;
        py = (py - lo1) * (2.f / (hi1 - lo1)) - 1.f;
        pz = (pz - lo2) * (2.f / (hi2 - lo2)) - 1.f;

        float p01[3], p02[3], p12[3];
        plane_interp(plane01, px, py, p01);
        plane_interp(plane02, px, pz, p02);
        plane_interp(plane12, py, pz, p12);
        float gx = p01[0] * p02[0] * p12[0];
        float gy = p01[1] * p02[1] * p12[1];
        float gz = p01[2] * p02[2] * p12[2];

        float qx = clampf((gx + 1.f) * (0.5f * 63.f), 0.f, 63.f);
        float qy = clampf((gy + 1.f) * (0.5f * 63.f), 0.f, 63.f);
        float qz = clampf((gz + 1.f) * (0.5f * 63.f), 0.f, 63.f);
        int ixg = (int)qx; if (ixg > 62) ixg = 62;
        int iyg = (int)qy; if (iyg > 62) iyg = 62;
        int izg = (int)qz; if (izg > 62) izg = 62;
        float fx = qx - (float)ixg, fy = qy - (float)iyg, fz = qz - (float)izg;
        float wx0 = 1.f - fx, wy0 = 1.f - fy, wz0 = 1.f - fz;
        u32x4 cw;
        cw[0] = pkh(wx0 * wy0 * wz0, wx0 * wy0 * fz);
        cw[1] = pkh(wx0 * fy  * wz0, wx0 * fy  * fz);
        cw[2] = pkh(fx  * wy0 * wz0, fx  * wy0 * fz);
        cw[3] = pkh(fx  * fy  * wz0, fx  * fy  * fz);
        s_cw[wv][s] = cw;
        // cell base as BYTE offset (u32): enables saddr-form gathers
        s_fb[wv][s] = (u32)(ixg * 4096 + iyg * 64 + izg) * 4u;
    }
    __syncthreads();   // weights + biases visible to all waves

    // relu C-regs, pack, b64-store to the swizzled [sample][dim] tile
#define RELUSTORE(ACC, NB) {                                           \
        u32x2 wr_;                                                     \
        wr_[0] = pk2bf(fmaxf((ACC)[0], 0.f), fmaxf((ACC)[1], 0.f));    \
        wr_[1] = pk2bf(fmaxf((ACC)[2], 0.f), fmaxf((ACC)[3], 0.f));    \
        *(u32x2*)&s_tile[wv][TSW(c16, (NB) * 16 + kg * 4)] = wr_; }

    const char* fby = (const char*)features;

    // ---- 8 chunks of 16 samples ----
#pragma unroll 1
    for (int c = 0; c < 8; ++c) {
        u32x4 cwp = s_cw[wv][c * 16 + c16];
        u32 fbB = s_fb[wv][c * 16 + c16];
        float2 w0p = uph(cwp[0]);
        float2 w1p = uph(cwp[1]);
        float2 w2p = uph(cwp[2]);
        float2 w3p = uph(cwp[3]);
        // this lane's channel-block base (byte offset): channel stride 1 MB
        u32 chb = fbB + (u32)(kg * 8) * 1048576u;

        // gather + trilinear combine -> B-operand (col=sample, k=channel)
        u32x4 a1v;
#pragma unroll
        for (int jj = 0; jj < 4; ++jj) {
            float vv[2];
#pragma unroll
            for (int h = 0; h < 2; ++h) {
                u32 off = chb + (u32)(jj * 2 + h) * 1048576u;
                f32x2u q0 = *(const f32x2u*)(fby + off);
                f32x2u q1 = *(const f32x2u*)(fby + off + 256);
                f32x2u q2 = *(const f32x2u*)(fby + off + 16384);
                f32x2u q3 = *(const f32x2u*)(fby + off + 16640);
                vv[h] = fmaf(w0p.x, q0[0], fmaf(w0p.y, q0[1],
                        fmaf(w1p.x, q1[0], fmaf(w1p.y, q1[1],
                        fmaf(w2p.x, q2[0], fmaf(w2p.y, q2[1],
                        fmaf(w3p.x, q3[0], w3p.y * q3[1])))))));
            }
            a1v[jj] = pk2bf(vv[0], vv[1]);
        }
        u16x8 a1 = __builtin_bit_cast(u16x8, a1v);

        // GEMM1 swapped: h^T = W1^T @ A1^T — TWO HALVES to cap live acc regs
        {
            f32x4 g0 = mfma_bf16(s_wfrag[0 * 64 + lane], a1, *(const f32x4*)&s_bias[0 * 16 + kg * 4]);
            f32x4 g1 = mfma_bf16(s_wfrag[1 * 64 + lane], a1, *(const f32x4*)&s_bias[1 * 16 + kg * 4]);
            RELUSTORE(g0, 0); RELUSTORE(g1, 1);
        }
        {
            f32x4 g2 = mfma_bf16(s_wfrag[2 * 64 + lane], a1, *(const f32x4*)&s_bias[2 * 16 + kg * 4]);
            f32x4 g3 = mfma_bf16(s_wfrag[3 * 64 + lane], a1, *(const f32x4*)&s_bias[3 * 16 + kg * 4]);
            RELUSTORE(g2, 2); RELUSTORE(g3, 3);
        }
        u16x8 B2_0 = *(const u16x8*)&s_tile[wv][TSW(c16, kg * 8)];
        u16x8 B2_1 = *(const u16x8*)&s_tile[wv][TSW(c16, 32 + kg * 8)];

        // GEMM2 swapped: so^T = W2^T @ h^T
        f32x4 so = mfma_bf16(AW2[0], B2_0, *(const f32x4*)&s_bias[64 + kg * 4]);
        so = mfma_bf16(AW2[1], B2_1, so);

        // density (so row 0 -> kg==0, q==0 lanes)
        if (kg == 0) {
            float dens = __expf(clampf(so[0], -15.f, 15.f));
            s_tau[wv][c * 16 + c16] = dens * delta;
        }

        // cin'^T B-fragment via 4-lane shuffle; rows 16..18 = dir, 19 = 1.0
        u32 Q0 = pk2bf(so[0], so[1]);
        u32 Q1 = pk2bf(so[2], so[3]);
        u32x4 ct;
        ct[0] = (u32)__shfl((int)Q0, sA);
        ct[1] = (u32)__shfl((int)Q1, sA);
        ct[2] = (u32)__shfl((int)Q0, sB);
        ct[3] = (u32)__shfl((int)Q1, sB);
        if (kg == 2) { ct[0] = dir01; ct[1] = dir2b; ct[2] = 0u; ct[3] = 0u; }
        if (kg == 3) { ct[0] = 0u; ct[1] = 0u; ct[2] = 0u; ct[3] = 0u; }
        u16x8 bcin = __builtin_bit_cast(u16x8, ct);

        // GEMM3 swapped: h2^T = Wc1'^T @ cin'^T — TWO HALVES (bias via row 19)
        {
            f32x4 zz; zz[0] = zz[1] = zz[2] = zz[3] = 0.f;
            f32x4 h0 = mfma_bf16(s_wfrag[256 + 0 * 64 + lane], bcin, zz);
            f32x4 h1 = mfma_bf16(s_wfrag[256 + 1 * 64 + lane], bcin, zz);
            RELUSTORE(h0, 0); RELUSTORE(h1, 1);
        }
        {
            f32x4 zz; zz[0] = zz[1] = zz[2] = zz[3] = 0.f;
            f32x4 h2 = mfma_bf16(s_wfrag[256 + 2 * 64 + lane], bcin, zz);
            f32x4 h3 = mfma_bf16(s_wfrag[256 + 3 * 64 + lane], bcin, zz);
            RELUSTORE(h2, 2); RELUSTORE(h3, 3);
        }
        u16x8 B4_0 = *(const u16x8*)&s_tile[wv][TSW(c16, kg * 8)];
        u16x8 B4_1 = *(const u16x8*)&s_tile[wv][TSW(c16, 32 + kg * 8)];

        // GEMM4 swapped: rgb^T = Wc2^T @ h2^T (bc2pad C-init from LDS)
        f32x4 cacc = mfma_bf16(AWc2[0], B4_0, *(const f32x4*)&s_bias[80 + kg * 4]);
        cacc = mfma_bf16(AWc2[1], B4_1, cacc);

        if (kg == 0) {
            int si = c * 16 + c16;
            float r = 1.f / (1.f + __expf(-cacc[0]));
            float g = 1.f / (1.f + __expf(-cacc[1]));
            float b = 1.f / (1.f + __expf(-cacc[2]));
            s_rgbrg[wv][si] = pkh(r, g);
            s_rgbb[wv][si] = (u16)(pkh(b, 0.f) & 0xffffu);
        }
    }
#undef RELUSTORE

    // ---- per-ray exponential integration (2 samples per lane) ----
    float t0 = s_tau[wv][lane];
    float t1 = s_tau[wv][64 + lane];
    float x0 = t0, x1 = t1;
#pragma unroll
    for (int off = 1; off < 64; off <<= 1) {
        float y = __shfl_up(x0, off);
        if (lane >= off) x0 += y;
    }
    float tot0 = __shfl(x0, 63);
#pragma unroll
    for (int off = 1; off < 64; off <<= 1) {
        float y = __shfl_up(x1, off);
        if (lane >= off) x1 += y;
    }
    x1 += tot0;

    float w0 = __expf(t0 - x0) * (1.f - __expf(-t0));
    float w1s = __expf(t1 - x1) * (1.f - __expf(-t1));

    float2 rg0 = uph(s_rgbrg[wv][lane]);
    float2 rg1 = uph(s_rgbrg[wv][64 + lane]);
    float bb0 = uph((u32)s_rgbb[wv][lane]).x;
    float bb1 = uph((u32)s_rgbb[wv][64 + lane]).x;

    float v0 = w0 * rg0.x + w1s * rg1.x;
    float v1 = w0 * rg0.y + w1s * rg1.y;
    float v2 = w0 * bb0 + w1s * bb1;
    float v3 = w0 + w1s;
#pragma unroll
    for (int off = 32; off; off >>= 1) {
        v0 += __shfl_xor(v0, off);
        v1 += __shfl_xor(v1, off);
        v2 += __shfl_xor(v2, off);
        v3 += __shfl_xor(v3, off);
    }
    if (lane == 0) {
        float bg = bg_color[0];
        out[ray * 3 + 0] = v0 + (1.f - v3) * bg;
        out[ray * 3 + 1] = v1 + (1.f - v3) * bg;
        out[ray * 3 + 2] = v2 + (1.f - v3) * bg;
    }
}

extern "C" void kernel_launch(void* const* d_in, const int* in_sizes, int n_in,
                              void* d_out, int out_size, void* d_ws, size_t ws_size,
                              hipStream_t stream) {
    const float* rays_o  = (const float*)d_in[0];
    const float* rays_d  = (const float*)d_in[1];
    const float* bg      = (const float*)d_in[2];
    const float* p01     = (const float*)d_in[3];
    const float* p02     = (const float*)d_in[4];
    const float* p12     = (const float*)d_in[5];
    const float* feats   = (const float*)d_in[6];
    const float* w1      = (const float*)d_in[7];
    const float* b1      = (const float*)d_in[8];
    const float* w2      = (const float*)d_in[9];
    const float* b2      = (const float*)d_in[10];
    const float* wc1     = (const float*)d_in[11];
    const float* bc1     = (const float*)d_in[12];
    const float* wc2     = (const float*)d_in[13];
    const float* bc2     = (const float*)d_in[14];
    const float* aabb    = (const float*)d_in[15];
    float* out = (float*)d_out;

    const int use_ws = (ws_size >= 6144 * sizeof(u16)) ? 1 : 0;
    u16* wsb = (u16*)d_ws;
    if (use_ws) {
        prep_weights<<<24, 256, 0, stream>>>(w1, wc1, w2, wc2, bc1, wsb);
    }
    nerf_mfma<<<NRAYS / 4, 256, 0, stream>>>(rays_o, rays_d, bg, p01, p02, p12, feats,
                                             w1, b1, w2, b2, wc1, bc1, wc2, bc2, aabb, out,
                                             wsb, use_ws);
}

// Round 16
// 92.168 us; speedup vs baseline: 1.1916x; 1.1916x over previous
//
#include <hip/hip_runtime.h>

#define NS 128
#define NRAYS 8192

typedef unsigned short u16;
typedef unsigned int   u32;
typedef unsigned short u16x8 __attribute__((ext_vector_type(8)));
typedef __bf16 b16x8 __attribute__((ext_vector_type(8)));
typedef float f32x4 __attribute__((ext_vector_type(4)));
typedef float f32x2 __attribute__((ext_vector_type(2)));
typedef _Float16 h16x2 __attribute__((ext_vector_type(2)));
typedef unsigned int u32x4 __attribute__((ext_vector_type(4)));
typedef unsigned int u32x2 __attribute__((ext_vector_type(2)));
typedef float f32x2u __attribute__((ext_vector_type(2), aligned(4)));

__device__ __forceinline__ float clampf(float x, float lo, float hi) {
    return fminf(fmaxf(x, lo), hi);
}

__device__ __forceinline__ u16 f2bf(float f) {
    return __builtin_bit_cast(u16, (__bf16)f);
}

// pack two f32 -> bf16 pair in one u32 (lo in bits 0-15)
__device__ __forceinline__ u32 pk2bf(float lo, float hi) {
    return (u32)f2bf(lo) | ((u32)f2bf(hi) << 16);
}

__device__ __forceinline__ u32 pkh(float a, float b) {
    h16x2 v; v[0] = (_Float16)a; v[1] = (_Float16)b;
    return __builtin_bit_cast(u32, v);
}
__device__ __forceinline__ float2 uph(u32 u) {
    h16x2 v = __builtin_bit_cast(h16x2, u);
    return make_float2((float)v[0], (float)v[1]);
}
// unpack f16x2 -> f32x2 vector (for packed math)
__device__ __forceinline__ f32x2 uph2(u32 u) {
    h16x2 v = __builtin_bit_cast(h16x2, u);
    f32x2 r; r[0] = (float)v[0]; r[1] = (float)v[1];
    return r;
}

__device__ __forceinline__ f32x4 mfma_bf16(u16x8 a, u16x8 b, f32x4 c) {
    return __builtin_amdgcn_mfma_f32_16x16x32_bf16(
        __builtin_bit_cast(b16x8, a), __builtin_bit_cast(b16x8, b), c, 0, 0, 0);
}

// swizzled u16-index into a [16][64] tile stored [sample][dim]
#define TSW(n, k) ((((n) * 64) + (k)) ^ (((n) & 7) << 3))

__device__ __forceinline__ void plane_interp(const float* __restrict__ g,
                                             float ca, float cb, float o[3]) {
    float pa = clampf((ca + 1.f) * (0.5f * 127.f), 0.f, 127.f);
    float pb = clampf((cb + 1.f) * (0.5f * 127.f), 0.f, 127.f);
    int la = (int)pa; if (la > 126) la = 126;
    int lb = (int)pb; if (lb > 126) lb = 126;
    float fa = pa - (float)la, fb = pb - (float)lb;
    const float* p = g + la * 128 + lb;
#pragma unroll
    for (int c = 0; c < 3; ++c) {
        const float* q = p + c * 16384;
        f32x2u q0 = *(const f32x2u*)q;
        f32x2u q1 = *(const f32x2u*)(q + 128);
        float top = fmaf(q0[1] - q0[0], fb, q0[0]);
        float bot = fmaf(q1[1] - q1[0], fb, q1[0]);
        o[c] = fmaf(bot - top, fa, top);
    }
}

// ---- prep: pack weight A-fragments (bf16, per-lane layout) into workspace ----
// AWc1' rows: [0]=0, [1..15]=wc1 so-rows, [16..18]=wc1 dir-rows, [19]=bc1 (bias
// row, pairs with cin' row19 == 1.0), [20..31]=0.
// layout (u16x8 units): [0,256) AW1 (nb*64+lane), [256,512) AWc1',
//                       [512,640) AW2 (ks*64+lane), [640,768) AWc2
__global__ __launch_bounds__(256)
void prep_weights(const float* __restrict__ w1, const float* __restrict__ wc1,
                  const float* __restrict__ w2, const float* __restrict__ wc2,
                  const float* __restrict__ bc1,
                  u16* __restrict__ wsb)
{
    int idx = blockIdx.x * 256 + threadIdx.x;   // 0..6143
    if (idx >= 6144) return;
    int lane = (idx >> 3) & 63;
    int j = idx & 7;
    int c16 = lane & 15, kg = lane >> 4;
    float v;
    if (idx < 2048) {                       // AW1
        int nb = idx >> 9;
        int k = kg * 8 + j;
        v = w1[k * 64 + nb * 16 + c16];
    } else if (idx < 4096) {                // AWc1' (permuted rows + bias row)
        int nb = (idx - 2048) >> 9;
        int k = kg * 8 + j;
        if (k == 0)       v = 0.f;
        else if (k < 16)  v = wc1[(k + 2) * 64 + nb * 16 + c16];
        else if (k < 19)  v = wc1[(k - 16) * 64 + nb * 16 + c16];
        else if (k == 19) v = bc1[nb * 16 + c16];
        else              v = 0.f;
    } else if (idx < 5120) {                // AW2
        int ks = (idx - 4096) >> 9;
        int k = ks * 32 + kg * 8 + j;
        v = w2[k * 16 + c16];
    } else {                                // AWc2 (M padded 3->16)
        int ks = (idx - 5120) >> 9;
        int k = ks * 32 + kg * 8 + j;
        v = (c16 < 3) ? wc2[k * 3 + c16] : 0.f;
    }
    wsb[idx] = f2bf(v);
}

// block = 4 rays, 4 waves, 1 wave = 1 ray, 8 chunks of 16 samples per wave.
// r14 structure (best: 93 µs) + VALU-count reduction: packed-f32 trilinear
// combine (v_pk_fma_f32), second uniform base to imm-fold corner offsets,
// packed relu (v_pk_max_f32). NO launch_bounds cap (r15: 128-reg cap spilled).
__global__ __launch_bounds__(256)
void nerf_mfma(const float* __restrict__ rays_o,
               const float* __restrict__ rays_d,
               const float* __restrict__ bg_color,
               const float* __restrict__ plane01,
               const float* __restrict__ plane02,
               const float* __restrict__ plane12,
               const float* __restrict__ features,
               const float* __restrict__ w1, const float* __restrict__ b1,
               const float* __restrict__ w2, const float* __restrict__ b2,
               const float* __restrict__ wc1, const float* __restrict__ bc1,
               const float* __restrict__ wc2, const float* __restrict__ bc2,
               const float* __restrict__ aabb,
               float* __restrict__ out,
               const u16* __restrict__ wsb, int use_ws)
{
    __shared__ __align__(16) u16x8 s_wfrag[512];        // AW1 + AWc1' (8 KB)
    __shared__ __align__(16) float s_bias[96];          // b1[64], b2[16], bc2pad[16]
    __shared__ __align__(16) u32x4 s_cw[4][128];        // trilinear corner weights
    __shared__ u32   s_fb[4][128];                      // cell base BYTE offsets
    __shared__ __align__(16) u16  s_tile[4][16 * 64];   // per-wave transpose tile
    __shared__ float s_tau[4][128];
    __shared__ u32   s_rgbrg[4][128];                   // f16 pair (r,g)
    __shared__ u16   s_rgbb[4][128];                    // f16 b

    const int tid  = threadIdx.x;
    const int wv   = tid >> 6;
    const int lane = tid & 63;
    const int c16  = lane & 15;
    const int kg   = lane >> 4;
    const int ray  = blockIdx.x * 4 + wv;
    const int sA   = c16 + 16 * ((2 * kg) & 3);
    const int sB   = c16 + 16 * ((2 * kg + 1) & 3);

    // ---- stage AW1/AWc1 to LDS; AW2/AWc2 to VGPRs ----
    u16x8 AW2[2], AWc2[2];
    if (use_ws) {
        const u16x8* wf = (const u16x8*)wsb;
#pragma unroll
        for (int i = 0; i < 2; ++i) s_wfrag[tid + 256 * i] = wf[tid + 256 * i];
#pragma unroll
        for (int ks = 0; ks < 2; ++ks) {
            AW2[ks]  = wf[512 + ks * 64 + lane];
            AWc2[ks] = wf[640 + ks * 64 + lane];
        }
    } else {
        if (wv == 0) {
#pragma unroll
            for (int nb = 0; nb < 4; ++nb) {
                u16x8 a, c;
#pragma unroll
                for (int j = 0; j < 8; ++j) {
                    int k = kg * 8 + j;
                    a[j] = f2bf(w1[k * 64 + nb * 16 + c16]);
                    float v;
                    if (k == 0)       v = 0.f;
                    else if (k < 16)  v = wc1[(k + 2) * 64 + nb * 16 + c16];
                    else if (k < 19)  v = wc1[(k - 16) * 64 + nb * 16 + c16];
                    else if (k == 19) v = bc1[nb * 16 + c16];
                    else              v = 0.f;
                    c[j] = f2bf(v);
                }
                s_wfrag[nb * 64 + lane] = a;
                s_wfrag[256 + nb * 64 + lane] = c;
            }
        }
#pragma unroll
        for (int ks = 0; ks < 2; ++ks)
#pragma unroll
            for (int j = 0; j < 8; ++j) {
                int k = ks * 32 + kg * 8 + j;
                AW2[ks][j]  = f2bf(w2[k * 16 + c16]);
                AWc2[ks][j] = f2bf(c16 < 3 ? wc2[k * 3 + c16] : 0.f);
            }
    }
    if (tid < 96) {
        float v;
        if (tid < 64)      v = b1[tid];
        else if (tid < 80) v = b2[tid - 64];
        else               v = (tid - 80 < 3) ? bc2[tid - 80] : 0.f;
        s_bias[tid] = v;
    }

    // ---- per-ray setup ----
    float ox = rays_o[ray * 3 + 0], oy = rays_o[ray * 3 + 1], oz = rays_o[ray * 3 + 2];
    float dx = rays_d[ray * 3 + 0], dy = rays_d[ray * 3 + 1], dz = rays_d[ray * 3 + 2];
    float rn = rsqrtf(dx * dx + dy * dy + dz * dz);
    dx *= rn; dy *= rn; dz *= rn;

    float lo0 = aabb[0], lo1 = aabb[1], lo2 = aabb[2];
    float hi0 = aabb[3], hi1 = aabb[4], hi2 = aabb[5];

    float invx = 1.f / dx, invy = 1.f / dy, invz = 1.f / dz;
    float tx0 = (lo0 - ox) * invx, tx1 = (hi0 - ox) * invx;
    float ty0 = (lo1 - oy) * invy, ty1 = (hi1 - oy) * invy;
    float tz0 = (lo2 - oz) * invz, tz1 = (hi2 - oz) * invz;
    float tnear = fmaxf(fmaxf(fminf(tx0, tx1), fminf(ty0, ty1)), fminf(tz0, tz1));
    tnear = fmaxf(tnear, 0.f);
    float tfar = fminf(fminf(fmaxf(tx0, tx1), fmaxf(ty0, ty1)), fmaxf(tz0, tz1));
    tfar = fmaxf(tfar, tnear);
    float delta = (tfar - tnear) * (1.f / (float)NS);

    // dir constants for cin' rows 16..18 + bias row 19 (kg==2 k-slice)
    const u32 dir01 = pk2bf(dx, dy);
    const u32 dir2b = pk2bf(dz, 1.0f);

    // ---- coordinate phase: this wave, 2 samples per lane ----
#pragma unroll
    for (int i = 0; i < 2; ++i) {
        int s = i * 64 + lane;
        float t = tnear + delta * ((float)s + 0.5f);
        float px = ox + dx * t, py = oy + dy * t, pz = oz + dz * t;
        px = (px - lo0) * (2.f / (hi0 - lo0)) - 1.f;
        py = (py - lo1) * (2.f / (hi1 - lo1)) - 1.f;
        pz = (pz - lo2) * (2.f / (hi2 - lo2)) - 1.f;

        float p01[3], p02[3], p12[3];
        plane_interp(plane01, px, py, p01);
        plane_interp(plane02, px, pz, p02);
        plane_interp(plane12, py, pz, p12);
        float gx = p01[0] * p02[0] * p12[0];
        float gy = p01[1] * p02[1] * p12[1];
        float gz = p01[2] * p02[2] * p12[2];

        float qx = clampf((gx + 1.f) * (0.5f * 63.f), 0.f, 63.f);
        float qy = clampf((gy + 1.f) * (0.5f * 63.f), 0.f, 63.f);
        float qz = clampf((gz + 1.f) * (0.5f * 63.f), 0.f, 63.f);
        int ixg = (int)qx; if (ixg > 62) ixg = 62;
        int iyg = (int)qy; if (iyg > 62) iyg = 62;
        int izg = (int)qz; if (izg > 62) izg = 62;
        float fx = qx - (float)ixg, fy = qy - (float)iyg, fz = qz - (float)izg;
        float wx0 = 1.f - fx, wy0 = 1.f - fy, wz0 = 1.f - fz;
        u32x4 cw;
        cw[0] = pkh(wx0 * wy0 * wz0, wx0 * wy0 * fz);
        cw[1] = pkh(wx0 * fy  * wz0, wx0 * fy  * fz);
        cw[2] = pkh(fx  * wy0 * wz0, fx  * wy0 * fz);
        cw[3] = pkh(fx  * fy  * wz0, fx  * fy  * fz);
        s_cw[wv][s] = cw;
        // cell base as BYTE offset (u32): enables saddr-form gathers
        s_fb[wv][s] = (u32)(ixg * 4096 + iyg * 64 + izg) * 4u;
    }
    __syncthreads();   // weights + biases visible to all waves

    // relu (packed) + pack to bf16 pairs, b64-store to swizzled tile
#define RELUSTORE(ACC, NB) {                                           \
        f32x2 lo_; lo_[0] = (ACC)[0]; lo_[1] = (ACC)[1];               \
        f32x2 hi_; hi_[0] = (ACC)[2]; hi_[1] = (ACC)[3];               \
        f32x2 z2_; z2_[0] = 0.f; z2_[1] = 0.f;                         \
        lo_ = __builtin_elementwise_max(lo_, z2_);                     \
        hi_ = __builtin_elementwise_max(hi_, z2_);                     \
        u32x2 wr_;                                                     \
        wr_[0] = pk2bf(lo_[0], lo_[1]);                                \
        wr_[1] = pk2bf(hi_[0], hi_[1]);                                \
        *(u32x2*)&s_tile[wv][TSW(c16, (NB) * 16 + kg * 4)] = wr_; }

    const char* fby  = (const char*)features;
    const char* fby2 = fby + 16384;   // second uniform base: folds +16384 offsets

    // ---- 8 chunks of 16 samples ----
#pragma unroll 1
    for (int c = 0; c < 8; ++c) {
        u32x4 cwp = s_cw[wv][c * 16 + c16];
        u32 fbB = s_fb[wv][c * 16 + c16];
        f32x2 w0v = uph2(cwp[0]);
        f32x2 w1v = uph2(cwp[1]);
        f32x2 w2v = uph2(cwp[2]);
        f32x2 w3v = uph2(cwp[3]);
        // this lane's channel-block base (byte offset): channel stride 1 MB
        u32 chb = fbB + (u32)(kg * 8) * 1048576u;

        // gather + packed trilinear combine -> B-operand (col=sample, k=channel)
        u32x4 a1v;
#pragma unroll
        for (int jj = 0; jj < 4; ++jj) {
            float vv[2];
#pragma unroll
            for (int h = 0; h < 2; ++h) {
                u32 off = chb + (u32)(jj * 2 + h) * 1048576u;
                f32x2 q0 = *(const f32x2u*)(fby + off);          // imm 0
                f32x2 q1 = *(const f32x2u*)(fby + off + 256);    // imm 256
                f32x2 q2 = *(const f32x2u*)(fby2 + off);         // imm 0 (base2)
                f32x2 q3 = *(const f32x2u*)(fby2 + off + 256);   // imm 256 (base2)
                f32x2 acc = q0 * w0v;
                acc = __builtin_elementwise_fma(q1, w1v, acc);
                acc = __builtin_elementwise_fma(q2, w2v, acc);
                acc = __builtin_elementwise_fma(q3, w3v, acc);
                vv[h] = acc[0] + acc[1];
            }
            a1v[jj] = pk2bf(vv[0], vv[1]);
        }
        u16x8 a1 = __builtin_bit_cast(u16x8, a1v);

        // GEMM1 swapped: h^T = W1^T @ A1^T (weights + b1 C-init from LDS)
        f32x4 g0 = mfma_bf16(s_wfrag[0 * 64 + lane], a1, *(const f32x4*)&s_bias[0 * 16 + kg * 4]);
        f32x4 g1 = mfma_bf16(s_wfrag[1 * 64 + lane], a1, *(const f32x4*)&s_bias[1 * 16 + kg * 4]);
        f32x4 g2 = mfma_bf16(s_wfrag[2 * 64 + lane], a1, *(const f32x4*)&s_bias[2 * 16 + kg * 4]);
        f32x4 g3 = mfma_bf16(s_wfrag[3 * 64 + lane], a1, *(const f32x4*)&s_bias[3 * 16 + kg * 4]);

        RELUSTORE(g0, 0); RELUSTORE(g1, 1); RELUSTORE(g2, 2); RELUSTORE(g3, 3);
        u16x8 B2_0 = *(const u16x8*)&s_tile[wv][TSW(c16, kg * 8)];
        u16x8 B2_1 = *(const u16x8*)&s_tile[wv][TSW(c16, 32 + kg * 8)];

        // GEMM2 swapped: so^T = W2^T @ h^T
        f32x4 so = mfma_bf16(AW2[0], B2_0, *(const f32x4*)&s_bias[64 + kg * 4]);
        so = mfma_bf16(AW2[1], B2_1, so);

        // density (so row 0 -> kg==0, q==0 lanes)
        if (kg == 0) {
            float dens = __expf(clampf(so[0], -15.f, 15.f));
            s_tau[wv][c * 16 + c16] = dens * delta;
        }

        // cin'^T B-fragment via 4-lane shuffle; rows 16..18 = dir, 19 = 1.0
        u32 Q0 = pk2bf(so[0], so[1]);
        u32 Q1 = pk2bf(so[2], so[3]);
        u32x4 ct;
        ct[0] = (u32)__shfl((int)Q0, sA);
        ct[1] = (u32)__shfl((int)Q1, sA);
        ct[2] = (u32)__shfl((int)Q0, sB);
        ct[3] = (u32)__shfl((int)Q1, sB);
        if (kg == 2) { ct[0] = dir01; ct[1] = dir2b; ct[2] = 0u; ct[3] = 0u; }
        if (kg == 3) { ct[0] = 0u; ct[1] = 0u; ct[2] = 0u; ct[3] = 0u; }
        u16x8 bcin = __builtin_bit_cast(u16x8, ct);

        // GEMM3 swapped: h2^T = Wc1'^T @ cin'^T (bias via weight row 19)
        f32x4 zz; zz[0] = zz[1] = zz[2] = zz[3] = 0.f;
        f32x4 h0 = mfma_bf16(s_wfrag[256 + 0 * 64 + lane], bcin, zz);
        f32x4 h1 = mfma_bf16(s_wfrag[256 + 1 * 64 + lane], bcin, zz);
        f32x4 h2 = mfma_bf16(s_wfrag[256 + 2 * 64 + lane], bcin, zz);
        f32x4 h3 = mfma_bf16(s_wfrag[256 + 3 * 64 + lane], bcin, zz);

        RELUSTORE(h0, 0); RELUSTORE(h1, 1); RELUSTORE(h2, 2); RELUSTORE(h3, 3);
        u16x8 B4_0 = *(const u16x8*)&s_tile[wv][TSW(c16, kg * 8)];
        u16x8 B4_1 = *(const u16x8*)&s_tile[wv][TSW(c16, 32 + kg * 8)];

        // GEMM4 swapped: rgb^T = Wc2^T @ h2^T (bc2pad C-init from LDS)
        f32x4 cacc = mfma_bf16(AWc2[0], B4_0, *(const f32x4*)&s_bias[80 + kg * 4]);
        cacc = mfma_bf16(AWc2[1], B4_1, cacc);

        if (kg == 0) {
            int si = c * 16 + c16;
            float r = 1.f / (1.f + __expf(-cacc[0]));
            float g = 1.f / (1.f + __expf(-cacc[1]));
            float b = 1.f / (1.f + __expf(-cacc[2]));
            s_rgbrg[wv][si] = pkh(r, g);
            s_rgbb[wv][si] = (u16)(pkh(b, 0.f) & 0xffffu);
        }
    }
#undef RELUSTORE

    // ---- per-ray exponential integration (2 samples per lane) ----
    float t0 = s_tau[wv][lane];
    float t1 = s_tau[wv][64 + lane];
    float x0 = t0, x1 = t1;
#pragma unroll
    for (int off = 1; off < 64; off <<= 1) {
        float y = __shfl_up(x0, off);
        if (lane >= off) x0 += y;
    }
    float tot0 = __shfl(x0, 63);
#pragma unroll
    for (int off = 1; off < 64; off <<= 1) {
        float y = __shfl_up(x1, off);
        if (lane >= off) x1 += y;
    }
    x1 += tot0;

    float w0 = __expf(t0 - x0) * (1.f - __expf(-t0));
    float w1s = __expf(t1 - x1) * (1.f - __expf(-t1));

    float2 rg0 = uph(s_rgbrg[wv][lane]);
    float2 rg1 = uph(s_rgbrg[wv][64 + lane]);
    float bb0 = uph((u32)s_rgbb[wv][lane]).x;
    float bb1 = uph((u32)s_rgbb[wv][64 + lane]).x;

    float v0 = w0 * rg0.x + w1s * rg1.x;
    float v1 = w0 * rg0.y + w1s * rg1.y;
    float v2 = w0 * bb0 + w1s * bb1;
    float v3 = w0 + w1s;
#pragma unroll
    for (int off = 32; off; off >>= 1) {
        v0 += __shfl_xor(v0, off);
        v1 += __shfl_xor(v1, off);
        v2 += __shfl_xor(v2, off);
        v3 += __shfl_xor(v3, off);
    }
    if (lane == 0) {
        float bg = bg_color[0];
        out[ray * 3 + 0] = v0 + (1.f - v3) * bg;
        out[ray * 3 + 1] = v1 + (1.f - v3) * bg;
        out[ray * 3 + 2] = v2 + (1.f - v3) * bg;
    }
}

extern "C" void kernel_launch(void* const* d_in, const int* in_sizes, int n_in,
                              void* d_out, int out_size, void* d_ws, size_t ws_size,
                              hipStream_t stream) {
    const float* rays_o  = (const float*)d_in[0];
    const float* rays_d  = (const float*)d_in[1];
    const float* bg      = (const float*)d_in[2];
    const float* p01     = (const float*)d_in[3];
    const float* p02     = (const float*)d_in[4];
    const float* p12     = (const float*)d_in[5];
    const float* feats   = (const float*)d_in[6];
    const float* w1      = (const float*)d_in[7];
    const float* b1      = (const float*)d_in[8];
    const float* w2      = (const float*)d_in[9];
    const float* b2      = (const float*)d_in[10];
    const float* wc1     = (const float*)d_in[11];
    const float* bc1     = (const float*)d_in[12];
    const float* wc2     = (const float*)d_in[13];
    const float* bc2     = (const float*)d_in[14];
    const float* aabb    = (const float*)d_in[15];
    float* out = (float*)d_out;

    const int use_ws = (ws_size >= 6144 * sizeof(u16)) ? 1 : 0;
    u16* wsb = (u16*)d_ws;
    if (use_ws) {
        prep_weights<<<24, 256, 0, stream>>>(w1, wc1, w2, wc2, bc1, wsb);
    }
    nerf_mfma<<<NRAYS / 4, 256, 0, stream>>>(rays_o, rays_d, bg, p01, p02, p12, feats,
                                             w1, b1, w2, b2, wc1, bc1, wc2, bc2, aabb, out,
                                             wsb, use_ws);
}

// Round 17
// 89.180 us; speedup vs baseline: 1.2315x; 1.0335x over previous
//
#include <hip/hip_runtime.h>

#define NS 128
#define NRAYS 8192
#define GRID_BYTES 16777216u   // 262144 voxels * 32 ch * 2 B

typedef unsigned short u16;
typedef unsigned int   u32;
typedef unsigned short u16x8 __attribute__((ext_vector_type(8)));
typedef __bf16 b16x8 __attribute__((ext_vector_type(8)));
typedef float f32x4 __attribute__((ext_vector_type(4)));
typedef float f32x2 __attribute__((ext_vector_type(2)));
typedef _Float16 h16x2 __attribute__((ext_vector_type(2)));
typedef unsigned int u32x4 __attribute__((ext_vector_type(4)));
typedef unsigned int u32x2 __attribute__((ext_vector_type(2)));
typedef float f32x2u __attribute__((ext_vector_type(2), aligned(4)));

__device__ __forceinline__ float clampf(float x, float lo, float hi) {
    return fminf(fmaxf(x, lo), hi);
}

__device__ __forceinline__ u16 f2bf(float f) {
    return __builtin_bit_cast(u16, (__bf16)f);
}

// pack two f32 -> bf16 pair in one u32 (lo in bits 0-15)
__device__ __forceinline__ u32 pk2bf(float lo, float hi) {
    return (u32)f2bf(lo) | ((u32)f2bf(hi) << 16);
}

__device__ __forceinline__ u32 pkh(float a, float b) {
    h16x2 v; v[0] = (_Float16)a; v[1] = (_Float16)b;
    return __builtin_bit_cast(u32, v);
}
__device__ __forceinline__ float2 uph(u32 u) {
    h16x2 v = __builtin_bit_cast(h16x2, u);
    return make_float2((float)v[0], (float)v[1]);
}
__device__ __forceinline__ f32x2 uph2(u32 u) {
    h16x2 v = __builtin_bit_cast(h16x2, u);
    f32x2 r; r[0] = (float)v[0]; r[1] = (float)v[1];
    return r;
}
// unpack a bf16 pair word -> f32x2 (lo = u<<16, hi = u & 0xffff0000)
__device__ __forceinline__ f32x2 up2(u32 u) {
    f32x2 r;
    r[0] = __builtin_bit_cast(float, u << 16);
    r[1] = __builtin_bit_cast(float, u & 0xffff0000u);
    return r;
}

__device__ __forceinline__ f32x4 mfma_bf16(u16x8 a, u16x8 b, f32x4 c) {
    return __builtin_amdgcn_mfma_f32_16x16x32_bf16(
        __builtin_bit_cast(b16x8, a), __builtin_bit_cast(b16x8, b), c, 0, 0, 0);
}

// swizzled u16-index into a [16][64] tile stored [sample][dim]
#define TSW(n, k) ((((n) * 64) + (k)) ^ (((n) & 7) << 3))

__device__ __forceinline__ void plane_interp(const float* __restrict__ g,
                                             float ca, float cb, float o[3]) {
    float pa = clampf((ca + 1.f) * (0.5f * 127.f), 0.f, 127.f);
    float pb = clampf((cb + 1.f) * (0.5f * 127.f), 0.f, 127.f);
    int la = (int)pa; if (la > 126) la = 126;
    int lb = (int)pb; if (lb > 126) lb = 126;
    float fa = pa - (float)la, fb = pb - (float)lb;
    const float* p = g + la * 128 + lb;
#pragma unroll
    for (int c = 0; c < 3; ++c) {
        const float* q = p + c * 16384;
        f32x2u q0 = *(const f32x2u*)q;
        f32x2u q1 = *(const f32x2u*)(q + 128);
        float top = fmaf(q0[1] - q0[0], fb, q0[0]);
        float bot = fmaf(q1[1] - q1[0], fb, q1[0]);
        o[c] = fmaf(bot - top, fa, top);
    }
}

// ---- prep: repack features [32][64^3] f32 -> [64^3][32] bf16 (channel-last) ----
__global__ __launch_bounds__(256)
void prep_grid(const float* __restrict__ f, u16* __restrict__ g)
{
    int vox = blockIdx.x * 256 + threadIdx.x;   // 0..262143
    u32 acc[16];
#pragma unroll
    for (int c = 0; c < 32; c += 2) {
        float a = f[(size_t)c * 262144 + vox];
        float b = f[(size_t)(c + 1) * 262144 + vox];
        acc[c >> 1] = pk2bf(a, b);
    }
    u32x4* o = (u32x4*)(g + (size_t)vox * 32);
#pragma unroll
    for (int k = 0; k < 4; ++k) {
        u32x4 w; w[0] = acc[k * 4]; w[1] = acc[k * 4 + 1];
        w[2] = acc[k * 4 + 2]; w[3] = acc[k * 4 + 3];
        o[k] = w;
    }
}

// ---- prep: pack weight A-fragments (bf16, per-lane layout) into workspace ----
// AWc1' rows: [0]=0, [1..15]=wc1 so-rows, [16..18]=wc1 dir-rows, [19]=bc1 (bias
// row, pairs with cin' row19 == 1.0), [20..31]=0.
__global__ __launch_bounds__(256)
void prep_weights(const float* __restrict__ w1, const float* __restrict__ wc1,
                  const float* __restrict__ w2, const float* __restrict__ wc2,
                  const float* __restrict__ bc1,
                  u16* __restrict__ wsb)
{
    int idx = blockIdx.x * 256 + threadIdx.x;   // 0..6143
    if (idx >= 6144) return;
    int lane = (idx >> 3) & 63;
    int j = idx & 7;
    int c16 = lane & 15, kg = lane >> 4;
    float v;
    if (idx < 2048) {                       // AW1
        int nb = idx >> 9;
        int k = kg * 8 + j;
        v = w1[k * 64 + nb * 16 + c16];
    } else if (idx < 4096) {                // AWc1' (permuted rows + bias row)
        int nb = (idx - 2048) >> 9;
        int k = kg * 8 + j;
        if (k == 0)       v = 0.f;
        else if (k < 16)  v = wc1[(k + 2) * 64 + nb * 16 + c16];
        else if (k < 19)  v = wc1[(k - 16) * 64 + nb * 16 + c16];
        else if (k == 19) v = bc1[nb * 16 + c16];
        else              v = 0.f;
    } else if (idx < 5120) {                // AW2
        int ks = (idx - 4096) >> 9;
        int k = ks * 32 + kg * 8 + j;
        v = w2[k * 16 + c16];
    } else {                                // AWc2 (M padded 3->16)
        int ks = (idx - 5120) >> 9;
        int k = ks * 32 + kg * 8 + j;
        v = (c16 < 3) ? wc2[k * 3 + c16] : 0.f;
    }
    wsb[idx] = f2bf(v);
}

// block = 4 rays, 4 waves, 1 wave = 1 ray, 8 chunks of 16 samples per wave.
// r16 structure + channel-last bf16 grid gather: 8x global_load_dwordx4 per
// chunk (one per trilinear corner; lane's 8 channels contiguous) instead of
// 32x 8-B loads — all 8 in flight at once, one vmcnt wait per chunk.
__global__ __launch_bounds__(256)
void nerf_mfma(const float* __restrict__ rays_o,
               const float* __restrict__ rays_d,
               const float* __restrict__ bg_color,
               const float* __restrict__ plane01,
               const float* __restrict__ plane02,
               const float* __restrict__ plane12,
               const float* __restrict__ features,
               const float* __restrict__ w1, const float* __restrict__ b1,
               const float* __restrict__ w2, const float* __restrict__ b2,
               const float* __restrict__ wc1, const float* __restrict__ bc1,
               const float* __restrict__ wc2, const float* __restrict__ bc2,
               const float* __restrict__ aabb,
               float* __restrict__ out,
               const u16* __restrict__ wsb, int use_wsb,
               const u16* __restrict__ wsg, int use_grid)
{
    __shared__ __align__(16) u16x8 s_wfrag[512];        // AW1 + AWc1' (8 KB)
    __shared__ __align__(16) float s_bias[96];          // b1[64], b2[16], bc2pad[16]
    __shared__ __align__(16) u32x4 s_cw[4][128];        // trilinear corner weights
    __shared__ u32   s_fb[4][128];                      // cell voxel indices
    __shared__ __align__(16) u16  s_tile[4][16 * 64];   // per-wave transpose tile
    __shared__ float s_tau[4][128];
    __shared__ u32   s_rgbrg[4][128];                   // f16 pair (r,g)
    __shared__ u16   s_rgbb[4][128];                    // f16 b

    const int tid  = threadIdx.x;
    const int wv   = tid >> 6;
    const int lane = tid & 63;
    const int c16  = lane & 15;
    const int kg   = lane >> 4;
    const int ray  = blockIdx.x * 4 + wv;
    const int sA   = c16 + 16 * ((2 * kg) & 3);
    const int sB   = c16 + 16 * ((2 * kg + 1) & 3);

    // ---- stage AW1/AWc1 to LDS; AW2/AWc2 to VGPRs ----
    u16x8 AW2[2], AWc2[2];
    if (use_wsb) {
        const u16x8* wf = (const u16x8*)wsb;
#pragma unroll
        for (int i = 0; i < 2; ++i) s_wfrag[tid + 256 * i] = wf[tid + 256 * i];
#pragma unroll
        for (int ks = 0; ks < 2; ++ks) {
            AW2[ks]  = wf[512 + ks * 64 + lane];
            AWc2[ks] = wf[640 + ks * 64 + lane];
        }
    } else {
        if (wv == 0) {
#pragma unroll
            for (int nb = 0; nb < 4; ++nb) {
                u16x8 a, c;
#pragma unroll
                for (int j = 0; j < 8; ++j) {
                    int k = kg * 8 + j;
                    a[j] = f2bf(w1[k * 64 + nb * 16 + c16]);
                    float v;
                    if (k == 0)       v = 0.f;
                    else if (k < 16)  v = wc1[(k + 2) * 64 + nb * 16 + c16];
                    else if (k < 19)  v = wc1[(k - 16) * 64 + nb * 16 + c16];
                    else if (k == 19) v = bc1[nb * 16 + c16];
                    else              v = 0.f;
                    c[j] = f2bf(v);
                }
                s_wfrag[nb * 64 + lane] = a;
                s_wfrag[256 + nb * 64 + lane] = c;
            }
        }
#pragma unroll
        for (int ks = 0; ks < 2; ++ks)
#pragma unroll
            for (int j = 0; j < 8; ++j) {
                int k = ks * 32 + kg * 8 + j;
                AW2[ks][j]  = f2bf(w2[k * 16 + c16]);
                AWc2[ks][j] = f2bf(c16 < 3 ? wc2[k * 3 + c16] : 0.f);
            }
    }
    if (tid < 96) {
        float v;
        if (tid < 64)      v = b1[tid];
        else if (tid < 80) v = b2[tid - 64];
        else               v = (tid - 80 < 3) ? bc2[tid - 80] : 0.f;
        s_bias[tid] = v;
    }

    // ---- per-ray setup ----
    float ox = rays_o[ray * 3 + 0], oy = rays_o[ray * 3 + 1], oz = rays_o[ray * 3 + 2];
    float dx = rays_d[ray * 3 + 0], dy = rays_d[ray * 3 + 1], dz = rays_d[ray * 3 + 2];
    float rn = rsqrtf(dx * dx + dy * dy + dz * dz);
    dx *= rn; dy *= rn; dz *= rn;

    float lo0 = aabb[0], lo1 = aabb[1], lo2 = aabb[2];
    float hi0 = aabb[3], hi1 = aabb[4], hi2 = aabb[5];

    float invx = 1.f / dx, invy = 1.f / dy, invz = 1.f / dz;
    float tx0 = (lo0 - ox) * invx, tx1 = (hi0 - ox) * invx;
    float ty0 = (lo1 - oy) * invy, ty1 = (hi1 - oy) * invy;
    float tz0 = (lo2 - oz) * invz, tz1 = (hi2 - oz) * invz;
    float tnear = fmaxf(fmaxf(fminf(tx0, tx1), fminf(ty0, ty1)), fminf(tz0, tz1));
    tnear = fmaxf(tnear, 0.f);
    float tfar = fminf(fminf(fmaxf(tx0, tx1), fmaxf(ty0, ty1)), fmaxf(tz0, tz1));
    tfar = fmaxf(tfar, tnear);
    float delta = (tfar - tnear) * (1.f / (float)NS);

    // dir constants for cin' rows 16..18 + bias row 19 (kg==2 k-slice)
    const u32 dir01 = pk2bf(dx, dy);
    const u32 dir2b = pk2bf(dz, 1.0f);

    // ---- coordinate phase: this wave, 2 samples per lane ----
#pragma unroll
    for (int i = 0; i < 2; ++i) {
        int s = i * 64 + lane;
        float t = tnear + delta * ((float)s + 0.5f);
        float px = ox + dx * t, py = oy + dy * t, pz = oz + dz * t;
        px = (px - lo0) * (2.f / (hi0 - lo0)) - 1.f;
        py = (py - lo1) * (2.f / (hi1 - lo1)) - 1.f;
        pz = (pz - lo2) * (2.f / (hi2 - lo2)) - 1.f;

        float p01[3], p02[3], p12[3];
        plane_interp(plane01, px, py, p01);
        plane_interp(plane02, px, pz, p02);
        plane_interp(plane12, py, pz, p12);
        float gx = p01[0] * p02[0] * p12[0];
        float gy = p01[1] * p02[1] * p12[1];
        float gz = p01[2] * p02[2] * p12[2];

        float qx = clampf((gx + 1.f) * (0.5f * 63.f), 0.f, 63.f);
        float qy = clampf((gy + 1.f) * (0.5f * 63.f), 0.f, 63.f);
        float qz = clampf((gz + 1.f) * (0.5f * 63.f), 0.f, 63.f);
        int ixg = (int)qx; if (ixg > 62) ixg = 62;
        int iyg = (int)qy; if (iyg > 62) iyg = 62;
        int izg = (int)qz; if (izg > 62) izg = 62;
        float fx = qx - (float)ixg, fy = qy - (float)iyg, fz = qz - (float)izg;
        float wx0 = 1.f - fx, wy0 = 1.f - fy, wz0 = 1.f - fz;
        u32x4 cw;
        cw[0] = pkh(wx0 * wy0 * wz0, wx0 * wy0 * fz);
        cw[1] = pkh(wx0 * fy  * wz0, wx0 * fy  * fz);
        cw[2] = pkh(fx  * wy0 * wz0, fx  * wy0 * fz);
        cw[3] = pkh(fx  * fy  * wz0, fx  * fy  * fz);
        s_cw[wv][s] = cw;
        s_fb[wv][s] = (u32)(ixg * 4096 + iyg * 64 + izg);   // raw voxel index
    }
    __syncthreads();   // weights + biases visible to all waves

    // relu (packed) + pack to bf16 pairs, b64-store to swizzled tile
#define RELUSTORE(ACC, NB) {                                           \
        f32x2 lo_; lo_[0] = (ACC)[0]; lo_[1] = (ACC)[1];               \
        f32x2 hi_; hi_[0] = (ACC)[2]; hi_[1] = (ACC)[3];               \
        f32x2 z2_; z2_[0] = 0.f; z2_[1] = 0.f;                         \
        lo_ = __builtin_elementwise_max(lo_, z2_);                     \
        hi_ = __builtin_elementwise_max(hi_, z2_);                     \
        u32x2 wr_;                                                     \
        wr_[0] = pk2bf(lo_[0], lo_[1]);                                \
        wr_[1] = pk2bf(hi_[0], hi_[1]);                                \
        *(u32x2*)&s_tile[wv][TSW(c16, (NB) * 16 + kg * 4)] = wr_; }

    // corner combine (channel-last path): scalar corner weight x 8 channels
#define CORNER(Q, W) {                                                 \
        f32x2 ws_; ws_[0] = (W); ws_[1] = (W);                         \
        p0 = __builtin_elementwise_fma(up2((Q)[0]), ws_, p0);          \
        p1 = __builtin_elementwise_fma(up2((Q)[1]), ws_, p1);          \
        p2 = __builtin_elementwise_fma(up2((Q)[2]), ws_, p2);          \
        p3 = __builtin_elementwise_fma(up2((Q)[3]), ws_, p3); }

    const char* fby  = (const char*)features;
    const char* fby2 = fby + 16384;
    const char* gby  = (const char*)wsg;

    // ---- 8 chunks of 16 samples ----
#pragma unroll 1
    for (int c = 0; c < 8; ++c) {
        u32x4 cwp = s_cw[wv][c * 16 + c16];
        u32 vidx = s_fb[wv][c * 16 + c16];
        f32x2 w0v = uph2(cwp[0]);
        f32x2 w1v = uph2(cwp[1]);
        f32x2 w2v = uph2(cwp[2]);
        f32x2 w3v = uph2(cwp[3]);

        u32x4 a1v;
        if (use_grid) {
            // channel-last bf16 grid: 8 corners x 1 dwordx4 each
            u32 o0  = vidx * 64u + (u32)(kg * 16);
            u32 oy  = o0 + 4096u;      // iy+1
            u32 ox  = o0 + 262144u;    // ix+1
            u32 oxy = o0 + 266240u;    // ix+1, iy+1
            u32x4 q00 = *(const u32x4*)(gby + o0);         // x0y0z0
            u32x4 q01 = *(const u32x4*)(gby + o0 + 64);    // x0y0z1
            u32x4 q10 = *(const u32x4*)(gby + oy);         // x0y1z0
            u32x4 q11 = *(const u32x4*)(gby + oy + 64);
            u32x4 q20 = *(const u32x4*)(gby + ox);         // x1y0z0
            u32x4 q21 = *(const u32x4*)(gby + ox + 64);
            u32x4 q30 = *(const u32x4*)(gby + oxy);        // x1y1z0
            u32x4 q31 = *(const u32x4*)(gby + oxy + 64);
            f32x2 p0, p1, p2, p3;
            p0[0] = p0[1] = 0.f; p1 = p0; p2 = p0; p3 = p0;
            CORNER(q00, w0v[0]); CORNER(q01, w0v[1]);
            CORNER(q10, w1v[0]); CORNER(q11, w1v[1]);
            CORNER(q20, w2v[0]); CORNER(q21, w2v[1]);
            CORNER(q30, w3v[0]); CORNER(q31, w3v[1]);
            a1v[0] = pk2bf(p0[0], p0[1]);
            a1v[1] = pk2bf(p1[0], p1[1]);
            a1v[2] = pk2bf(p2[0], p2[1]);
            a1v[3] = pk2bf(p3[0], p3[1]);
        } else {
            // fallback: original f32 channel-planar gather
            u32 chb = vidx * 4u + (u32)(kg * 8) * 1048576u;
#pragma unroll
            for (int jj = 0; jj < 4; ++jj) {
                float vv[2];
#pragma unroll
                for (int h = 0; h < 2; ++h) {
                    u32 off = chb + (u32)(jj * 2 + h) * 1048576u;
                    f32x2 q0 = *(const f32x2u*)(fby + off);
                    f32x2 q1 = *(const f32x2u*)(fby + off + 256);
                    f32x2 q2 = *(const f32x2u*)(fby2 + off);
                    f32x2 q3 = *(const f32x2u*)(fby2 + off + 256);
                    f32x2 acc = q0 * w0v;
                    acc = __builtin_elementwise_fma(q1, w1v, acc);
                    acc = __builtin_elementwise_fma(q2, w2v, acc);
                    acc = __builtin_elementwise_fma(q3, w3v, acc);
                    vv[h] = acc[0] + acc[1];
                }
                a1v[jj] = pk2bf(vv[0], vv[1]);
            }
        }
        u16x8 a1 = __builtin_bit_cast(u16x8, a1v);

        // GEMM1 swapped: h^T = W1^T @ A1^T (weights + b1 C-init from LDS)
        f32x4 g0 = mfma_bf16(s_wfrag[0 * 64 + lane], a1, *(const f32x4*)&s_bias[0 * 16 + kg * 4]);
        f32x4 g1 = mfma_bf16(s_wfrag[1 * 64 + lane], a1, *(const f32x4*)&s_bias[1 * 16 + kg * 4]);
        f32x4 g2 = mfma_bf16(s_wfrag[2 * 64 + lane], a1, *(const f32x4*)&s_bias[2 * 16 + kg * 4]);
        f32x4 g3 = mfma_bf16(s_wfrag[3 * 64 + lane], a1, *(const f32x4*)&s_bias[3 * 16 + kg * 4]);

        RELUSTORE(g0, 0); RELUSTORE(g1, 1); RELUSTORE(g2, 2); RELUSTORE(g3, 3);
        u16x8 B2_0 = *(const u16x8*)&s_tile[wv][TSW(c16, kg * 8)];
        u16x8 B2_1 = *(const u16x8*)&s_tile[wv][TSW(c16, 32 + kg * 8)];

        // GEMM2 swapped: so^T = W2^T @ h^T
        f32x4 so = mfma_bf16(AW2[0], B2_0, *(const f32x4*)&s_bias[64 + kg * 4]);
        so = mfma_bf16(AW2[1], B2_1, so);

        // density (so row 0 -> kg==0, q==0 lanes)
        if (kg == 0) {
            float dens = __expf(clampf(so[0], -15.f, 15.f));
            s_tau[wv][c * 16 + c16] = dens * delta;
        }

        // cin'^T B-fragment via 4-lane shuffle; rows 16..18 = dir, 19 = 1.0
        u32 Q0 = pk2bf(so[0], so[1]);
        u32 Q1 = pk2bf(so[2], so[3]);
        u32x4 ct;
        ct[0] = (u32)__shfl((int)Q0, sA);
        ct[1] = (u32)__shfl((int)Q1, sA);
        ct[2] = (u32)__shfl((int)Q0, sB);
        ct[3] = (u32)__shfl((int)Q1, sB);
        if (kg == 2) { ct[0] = dir01; ct[1] = dir2b; ct[2] = 0u; ct[3] = 0u; }
        if (kg == 3) { ct[0] = 0u; ct[1] = 0u; ct[2] = 0u; ct[3] = 0u; }
        u16x8 bcin = __builtin_bit_cast(u16x8, ct);

        // GEMM3 swapped: h2^T = Wc1'^T @ cin'^T (bias via weight row 19)
        f32x4 zz; zz[0] = zz[1] = zz[2] = zz[3] = 0.f;
        f32x4 h0 = mfma_bf16(s_wfrag[256 + 0 * 64 + lane], bcin, zz);
        f32x4 h1 = mfma_bf16(s_wfrag[256 + 1 * 64 + lane], bcin, zz);
        f32x4 h2 = mfma_bf16(s_wfrag[256 + 2 * 64 + lane], bcin, zz);
        f32x4 h3 = mfma_bf16(s_wfrag[256 + 3 * 64 + lane], bcin, zz);

        RELUSTORE(h0, 0); RELUSTORE(h1, 1); RELUSTORE(h2, 2); RELUSTORE(h3, 3);
        u16x8 B4_0 = *(const u16x8*)&s_tile[wv][TSW(c16, kg * 8)];
        u16x8 B4_1 = *(const u16x8*)&s_tile[wv][TSW(c16, 32 + kg * 8)];

        // GEMM4 swapped: rgb^T = Wc2^T @ h2^T (bc2pad C-init from LDS)
        f32x4 cacc = mfma_bf16(AWc2[0], B4_0, *(const f32x4*)&s_bias[80 + kg * 4]);
        cacc = mfma_bf16(AWc2[1], B4_1, cacc);

        if (kg == 0) {
            int si = c * 16 + c16;
            float r = 1.f / (1.f + __expf(-cacc[0]));
            float g = 1.f / (1.f + __expf(-cacc[1]));
            float b = 1.f / (1.f + __expf(-cacc[2]));
            s_rgbrg[wv][si] = pkh(r, g);
            s_rgbb[wv][si] = (u16)(pkh(b, 0.f) & 0xffffu);
        }
    }
#undef RELUSTORE
#undef CORNER

    // ---- per-ray exponential integration (2 samples per lane) ----
    float t0 = s_tau[wv][lane];
    float t1 = s_tau[wv][64 + lane];
    float x0 = t0, x1 = t1;
#pragma unroll
    for (int off = 1; off < 64; off <<= 1) {
        float y = __shfl_up(x0, off);
        if (lane >= off) x0 += y;
    }
    float tot0 = __shfl(x0, 63);
#pragma unroll
    for (int off = 1; off < 64; off <<= 1) {
        float y = __shfl_up(x1, off);
        if (lane >= off) x1 += y;
    }
    x1 += tot0;

    float w0 = __expf(t0 - x0) * (1.f - __expf(-t0));
    float w1s = __expf(t1 - x1) * (1.f - __expf(-t1));

    float2 rg0 = uph(s_rgbrg[wv][lane]);
    float2 rg1 = uph(s_rgbrg[wv][64 + lane]);
    float bb0 = uph((u32)s_rgbb[wv][lane]).x;
    float bb1 = uph((u32)s_rgbb[wv][64 + lane]).x;

    float v0 = w0 * rg0.x + w1s * rg1.x;
    float v1 = w0 * rg0.y + w1s * rg1.y;
    float v2 = w0 * bb0 + w1s * bb1;
    float v3 = w0 + w1s;
#pragma unroll
    for (int off = 32; off; off >>= 1) {
        v0 += __shfl_xor(v0, off);
        v1 += __shfl_xor(v1, off);
        v2 += __shfl_xor(v2, off);
        v3 += __shfl_xor(v3, off);
    }
    if (lane == 0) {
        float bg = bg_color[0];
        out[ray * 3 + 0] = v0 + (1.f - v3) * bg;
        out[ray * 3 + 1] = v1 + (1.f - v3) * bg;
        out[ray * 3 + 2] = v2 + (1.f - v3) * bg;
    }
}

extern "C" void kernel_launch(void* const* d_in, const int* in_sizes, int n_in,
                              void* d_out, int out_size, void* d_ws, size_t ws_size,
                              hipStream_t stream) {
    const float* rays_o  = (const float*)d_in[0];
    const float* rays_d  = (const float*)d_in[1];
    const float* bg      = (const float*)d_in[2];
    const float* p01     = (const float*)d_in[3];
    const float* p02     = (const float*)d_in[4];
    const float* p12     = (const float*)d_in[5];
    const float* feats   = (const float*)d_in[6];
    const float* w1      = (const float*)d_in[7];
    const float* b1      = (const float*)d_in[8];
    const float* w2      = (const float*)d_in[9];
    const float* b2      = (const float*)d_in[10];
    const float* wc1     = (const float*)d_in[11];
    const float* bc1     = (const float*)d_in[12];
    const float* wc2     = (const float*)d_in[13];
    const float* bc2     = (const float*)d_in[14];
    const float* aabb    = (const float*)d_in[15];
    float* out = (float*)d_out;

    const int use_grid = (ws_size >= (size_t)GRID_BYTES + 12288) ? 1 : 0;
    const int use_wsb  = (use_grid || ws_size >= 12288) ? 1 : 0;
    u16* wsg = (u16*)d_ws;
    u16* wsb = use_grid ? (u16*)((char*)d_ws + GRID_BYTES) : (u16*)d_ws;

    if (use_grid) {
        prep_grid<<<1024, 256, 0, stream>>>(feats, wsg);
    }
    if (use_wsb) {
        prep_weights<<<24, 256, 0, stream>>>(w1, wc1, w2, wc2, bc1, wsb);
    }
    nerf_mfma<<<NRAYS / 4, 256, 0, stream>>>(rays_o, rays_d, bg, p01, p02, p12, feats,
                                             w1, b1, w2, b2, wc1, bc1, wc2, bc2, aabb, out,
                                             wsb, use_wsb, wsg, use_grid);
}

// Round 19
// 82.047 us; speedup vs baseline: 1.3386x; 1.0869x over previous
//
#include <hip/hip_runtime.h>

#define NS 128
#define NRAYS 8192
#define GRID_BYTES 16777216u   // 262144 voxels * 32 ch * 2 B

typedef unsigned short u16;
typedef unsigned int   u32;
typedef unsigned short u16x8 __attribute__((ext_vector_type(8)));
typedef __bf16 b16x8 __attribute__((ext_vector_type(8)));
typedef float f32x4 __attribute__((ext_vector_type(4)));
typedef float f32x2 __attribute__((ext_vector_type(2)));
typedef _Float16 h16x2 __attribute__((ext_vector_type(2)));
typedef unsigned int u32x4 __attribute__((ext_vector_type(4)));
typedef unsigned int u32x2 __attribute__((ext_vector_type(2)));
typedef float f32x2u __attribute__((ext_vector_type(2), aligned(4)));

__device__ __forceinline__ float clampf(float x, float lo, float hi) {
    return fminf(fmaxf(x, lo), hi);
}

__device__ __forceinline__ u16 f2bf(float f) {
    return __builtin_bit_cast(u16, (__bf16)f);
}

__device__ __forceinline__ u32 pk2bf(float lo, float hi) {
    return (u32)f2bf(lo) | ((u32)f2bf(hi) << 16);
}

__device__ __forceinline__ u32 pkh(float a, float b) {
    h16x2 v; v[0] = (_Float16)a; v[1] = (_Float16)b;
    return __builtin_bit_cast(u32, v);
}
__device__ __forceinline__ float2 uph(u32 u) {
    h16x2 v = __builtin_bit_cast(h16x2, u);
    return make_float2((float)v[0], (float)v[1]);
}
__device__ __forceinline__ f32x2 uph2(u32 u) {
    h16x2 v = __builtin_bit_cast(h16x2, u);
    f32x2 r; r[0] = (float)v[0]; r[1] = (float)v[1];
    return r;
}
// unpack a bf16 pair word -> f32x2
__device__ __forceinline__ f32x2 up2(u32 u) {
    f32x2 r;
    r[0] = __builtin_bit_cast(float, u << 16);
    r[1] = __builtin_bit_cast(float, u & 0xffff0000u);
    return r;
}

__device__ __forceinline__ f32x4 mfma_bf16(u16x8 a, u16x8 b, f32x4 c) {
    return __builtin_amdgcn_mfma_f32_16x16x32_bf16(
        __builtin_bit_cast(b16x8, a), __builtin_bit_cast(b16x8, b), c, 0, 0, 0);
}

#define TSW(n, k) ((((n) * 64) + (k)) ^ (((n) & 7) << 3))

__device__ __forceinline__ void plane_interp(const float* __restrict__ g,
                                             float ca, float cb, float o[3]) {
    float pa = clampf((ca + 1.f) * (0.5f * 127.f), 0.f, 127.f);
    float pb = clampf((cb + 1.f) * (0.5f * 127.f), 0.f, 127.f);
    int la = (int)pa; if (la > 126) la = 126;
    int lb = (int)pb; if (lb > 126) lb = 126;
    float fa = pa - (float)la, fb = pb - (float)lb;
    const float* p = g + la * 128 + lb;
#pragma unroll
    for (int c = 0; c < 3; ++c) {
        const float* q = p + c * 16384;
        f32x2u q0 = *(const f32x2u*)q;
        f32x2u q1 = *(const f32x2u*)(q + 128);
        float top = fmaf(q0[1] - q0[0], fb, q0[0]);
        float bot = fmaf(q1[1] - q1[0], fb, q1[0]);
        o[c] = fmaf(bot - top, fa, top);
    }
}

// ---- prep: repack features [32][64^3] f32 -> [64^3][32] bf16 ----
__global__ __launch_bounds__(256)
void prep_grid(const float* __restrict__ f, u16* __restrict__ g)
{
    int vox = blockIdx.x * 256 + threadIdx.x;
    u32 acc[16];
#pragma unroll
    for (int c = 0; c < 32; c += 2) {
        float a = f[(size_t)c * 262144 + vox];
        float b = f[(size_t)(c + 1) * 262144 + vox];
        acc[c >> 1] = pk2bf(a, b);
    }
    u32x4* o = (u32x4*)(g + (size_t)vox * 32);
#pragma unroll
    for (int k = 0; k < 4; ++k) {
        u32x4 w; w[0] = acc[k * 4]; w[1] = acc[k * 4 + 1];
        w[2] = acc[k * 4 + 2]; w[3] = acc[k * 4 + 3];
        o[k] = w;
    }
}

// ---- prep: pack weight A-fragments into workspace ----
__global__ __launch_bounds__(256)
void prep_weights(const float* __restrict__ w1, const float* __restrict__ wc1,
                  const float* __restrict__ w2, const float* __restrict__ wc2,
                  const float* __restrict__ bc1,
                  u16* __restrict__ wsb)
{
    int idx = blockIdx.x * 256 + threadIdx.x;
    if (idx >= 6144) return;
    int lane = (idx >> 3) & 63;
    int j = idx & 7;
    int c16 = lane & 15, kg = lane >> 4;
    float v;
    if (idx < 2048) {
        int nb = idx >> 9;
        int k = kg * 8 + j;
        v = w1[k * 64 + nb * 16 + c16];
    } else if (idx < 4096) {
        int nb = (idx - 2048) >> 9;
        int k = kg * 8 + j;
        if (k == 0)       v = 0.f;
        else if (k < 16)  v = wc1[(k + 2) * 64 + nb * 16 + c16];
        else if (k < 19)  v = wc1[(k - 16) * 64 + nb * 16 + c16];
        else if (k == 19) v = bc1[nb * 16 + c16];
        else              v = 0.f;
    } else if (idx < 5120) {
        int ks = (idx - 4096) >> 9;
        int k = ks * 32 + kg * 8 + j;
        v = w2[k * 16 + c16];
    } else {
        int ks = (idx - 5120) >> 9;
        int k = ks * 32 + kg * 8 + j;
        v = (c16 < 3) ? wc2[k * 3 + c16] : 0.f;
    }
    wsb[idx] = f2bf(v);
}

#define RELUSTORE(ACC, NB) {                                           \
        f32x2 lo_; lo_[0] = (ACC)[0]; lo_[1] = (ACC)[1];               \
        f32x2 hi_; hi_[0] = (ACC)[2]; hi_[1] = (ACC)[3];               \
        f32x2 z2_; z2_[0] = 0.f; z2_[1] = 0.f;                         \
        lo_ = __builtin_elementwise_max(lo_, z2_);                     \
        hi_ = __builtin_elementwise_max(hi_, z2_);                     \
        u32x2 wr_;                                                     \
        wr_[0] = pk2bf(lo_[0], lo_[1]);                                \
        wr_[1] = pk2bf(hi_[0], hi_[1]);                                \
        *(u32x2*)&s_tile[wv][TSW(c16, (NB) * 16 + kg * 4)] = wr_; }

#define CORNER(Q, W) {                                                 \
        f32x2 ws_; ws_[0] = (W); ws_[1] = (W);                         \
        p0 = __builtin_elementwise_fma(up2((Q)[0]), ws_, p0);          \
        p1 = __builtin_elementwise_fma(up2((Q)[1]), ws_, p1);          \
        p2 = __builtin_elementwise_fma(up2((Q)[2]), ws_, p2);          \
        p3 = __builtin_elementwise_fma(up2((Q)[3]), ws_, p3); }

// shared prologue/epilogue; VARIADIC so commas inside the gather block are safe
#define KERNEL_BODY(...)                                               \
    __shared__ __align__(16) u16x8 s_wfrag[512];                       \
    __shared__ __align__(16) float s_bias[96];                         \
    __shared__ __align__(16) u32x4 s_cw[4][128];                       \
    __shared__ u32   s_fb[4][128];                                     \
    __shared__ __align__(16) u16  s_tile[4][16 * 64];                  \
    __shared__ float s_tau[4][128];                                    \
    __shared__ u32   s_rgbrg[4][128];                                  \
    __shared__ u16   s_rgbb[4][128];                                   \
    const int tid  = threadIdx.x;                                      \
    const int wv   = tid >> 6;                                         \
    const int lane = tid & 63;                                         \
    const int c16  = lane & 15;                                        \
    const int kg   = lane >> 4;                                        \
    const int ray  = blockIdx.x * 4 + wv;                              \
    const int sA   = c16 + 16 * ((2 * kg) & 3);                        \
    const int sB   = c16 + 16 * ((2 * kg + 1) & 3);                    \
    u16x8 AW2[2], AWc2[2];                                             \
    {                                                                  \
        const u16x8* wf = (const u16x8*)wsb;                           \
        _Pragma("unroll")                                              \
        for (int i = 0; i < 2; ++i)                                    \
            s_wfrag[tid + 256 * i] = wf[tid + 256 * i];                \
        _Pragma("unroll")                                              \
        for (int ks = 0; ks < 2; ++ks) {                               \
            AW2[ks]  = wf[512 + ks * 64 + lane];                       \
            AWc2[ks] = wf[640 + ks * 64 + lane];                       \
        }                                                              \
    }                                                                  \
    if (tid < 96) {                                                    \
        float v;                                                       \
        if (tid < 64)      v = b1[tid];                                \
        else if (tid < 80) v = b2[tid - 64];                           \
        else               v = (tid - 80 < 3) ? bc2[tid - 80] : 0.f;   \
        s_bias[tid] = v;                                               \
    }                                                                  \
    float ox = rays_o[ray * 3 + 0], oy = rays_o[ray * 3 + 1], oz = rays_o[ray * 3 + 2]; \
    float dx = rays_d[ray * 3 + 0], dy = rays_d[ray * 3 + 1], dz = rays_d[ray * 3 + 2]; \
    float rn = rsqrtf(dx * dx + dy * dy + dz * dz);                    \
    dx *= rn; dy *= rn; dz *= rn;                                      \
    float lo0 = aabb[0], lo1 = aabb[1], lo2 = aabb[2];                 \
    float hi0 = aabb[3], hi1 = aabb[4], hi2 = aabb[5];                 \
    float invx = 1.f / dx, invy = 1.f / dy, invz = 1.f / dz;           \
    float tx0 = (lo0 - ox) * invx, tx1 = (hi0 - ox) * invx;            \
    float ty0 = (lo1 - oy) * invy, ty1 = (hi1 - oy) * invy;            \
    float tz0 = (lo2 - oz) * invz, tz1 = (hi2 - oz) * invz;            \
    float tnear = fmaxf(fmaxf(fminf(tx0, tx1), fminf(ty0, ty1)), fminf(tz0, tz1)); \
    tnear = fmaxf(tnear, 0.f);                                         \
    float tfar = fminf(fminf(fmaxf(tx0, tx1), fmaxf(ty0, ty1)), fmaxf(tz0, tz1)); \
    tfar = fmaxf(tfar, tnear);                                         \
    float delta = (tfar - tnear) * (1.f / (float)NS);                  \
    const u32 dir01 = pk2bf(dx, dy);                                   \
    const u32 dir2b = pk2bf(dz, 1.0f);                                 \
    _Pragma("unroll")                                                  \
    for (int i = 0; i < 2; ++i) {                                      \
        int s = i * 64 + lane;                                         \
        float t = tnear + delta * ((float)s + 0.5f);                   \
        float px = ox + dx * t, py = oy + dy * t, pz = oz + dz * t;    \
        px = (px - lo0) * (2.f / (hi0 - lo0)) - 1.f;                   \
        py = (py - lo1) * (2.f / (hi1 - lo1)) - 1.f;                   \
        pz = (pz - lo2) * (2.f / (hi2 - lo2)) - 1.f;                   \
        float p01[3], p02[3], p12[3];                                  \
        plane_interp(plane01, px, py, p01);                            \
        plane_interp(plane02, px, pz, p02);                            \
        plane_interp(plane12, py, pz, p12);                            \
        float gx = p01[0] * p02[0] * p12[0];                           \
        float gy = p01[1] * p02[1] * p12[1];                           \
        float gz = p01[2] * p02[2] * p12[2];                           \
        float qx = clampf((gx + 1.f) * (0.5f * 63.f), 0.f, 63.f);      \
        float qy = clampf((gy + 1.f) * (0.5f * 63.f), 0.f, 63.f);      \
        float qz = clampf((gz + 1.f) * (0.5f * 63.f), 0.f, 63.f);      \
        int ixg = (int)qx; if (ixg > 62) ixg = 62;                     \
        int iyg = (int)qy; if (iyg > 62) iyg = 62;                     \
        int izg = (int)qz; if (izg > 62) izg = 62;                     \
        float fx = qx - (float)ixg, fy = qy - (float)iyg, fz = qz - (float)izg; \
        float wx0 = 1.f - fx, wy0 = 1.f - fy, wz0 = 1.f - fz;          \
        u32x4 cw;                                                      \
        cw[0] = pkh(wx0 * wy0 * wz0, wx0 * wy0 * fz);                  \
        cw[1] = pkh(wx0 * fy  * wz0, wx0 * fy  * fz);                  \
        cw[2] = pkh(fx  * wy0 * wz0, fx  * wy0 * fz);                  \
        cw[3] = pkh(fx  * fy  * wz0, fx  * fy  * fz);                  \
        s_cw[wv][s] = cw;                                              \
        s_fb[wv][s] = (u32)(ixg * 4096 + iyg * 64 + izg);              \
    }                                                                  \
    __syncthreads();                                                   \
    _Pragma("unroll 1")                                                \
    for (int c = 0; c < 8; ++c) {                                      \
        u32x4 cwp = s_cw[wv][c * 16 + c16];                            \
        u32 vidx = s_fb[wv][c * 16 + c16];                             \
        f32x2 w0v = uph2(cwp[0]);                                      \
        f32x2 w1v = uph2(cwp[1]);                                      \
        f32x2 w2v = uph2(cwp[2]);                                      \
        f32x2 w3v = uph2(cwp[3]);                                      \
        u32x4 a1v;                                                     \
        { __VA_ARGS__ }                                                \
        u16x8 a1 = __builtin_bit_cast(u16x8, a1v);                     \
        f32x4 g0 = mfma_bf16(s_wfrag[0 * 64 + lane], a1, *(const f32x4*)&s_bias[0 * 16 + kg * 4]); \
        f32x4 g1 = mfma_bf16(s_wfrag[1 * 64 + lane], a1, *(const f32x4*)&s_bias[1 * 16 + kg * 4]); \
        f32x4 g2 = mfma_bf16(s_wfrag[2 * 64 + lane], a1, *(const f32x4*)&s_bias[2 * 16 + kg * 4]); \
        f32x4 g3 = mfma_bf16(s_wfrag[3 * 64 + lane], a1, *(const f32x4*)&s_bias[3 * 16 + kg * 4]); \
        RELUSTORE(g0, 0); RELUSTORE(g1, 1); RELUSTORE(g2, 2); RELUSTORE(g3, 3); \
        u16x8 B2_0 = *(const u16x8*)&s_tile[wv][TSW(c16, kg * 8)];     \
        u16x8 B2_1 = *(const u16x8*)&s_tile[wv][TSW(c16, 32 + kg * 8)];\
        f32x4 so = mfma_bf16(AW2[0], B2_0, *(const f32x4*)&s_bias[64 + kg * 4]); \
        so = mfma_bf16(AW2[1], B2_1, so);                              \
        if (kg == 0) {                                                 \
            float dens = __expf(clampf(so[0], -15.f, 15.f));           \
            s_tau[wv][c * 16 + c16] = dens * delta;                    \
        }                                                              \
        u32 Q0 = pk2bf(so[0], so[1]);                                  \
        u32 Q1 = pk2bf(so[2], so[3]);                                  \
        u32x4 ct;                                                      \
        ct[0] = (u32)__shfl((int)Q0, sA);                              \
        ct[1] = (u32)__shfl((int)Q1, sA);                              \
        ct[2] = (u32)__shfl((int)Q0, sB);                              \
        ct[3] = (u32)__shfl((int)Q1, sB);                              \
        if (kg == 2) { ct[0] = dir01; ct[1] = dir2b; ct[2] = 0u; ct[3] = 0u; } \
        if (kg == 3) { ct[0] = 0u; ct[1] = 0u; ct[2] = 0u; ct[3] = 0u; } \
        u16x8 bcin = __builtin_bit_cast(u16x8, ct);                    \
        f32x4 zz; zz[0] = zz[1] = zz[2] = zz[3] = 0.f;                 \
        f32x4 h0 = mfma_bf16(s_wfrag[256 + 0 * 64 + lane], bcin, zz);  \
        f32x4 h1 = mfma_bf16(s_wfrag[256 + 1 * 64 + lane], bcin, zz);  \
        f32x4 h2 = mfma_bf16(s_wfrag[256 + 2 * 64 + lane], bcin, zz);  \
        f32x4 h3 = mfma_bf16(s_wfrag[256 + 3 * 64 + lane], bcin, zz);  \
        RELUSTORE(h0, 0); RELUSTORE(h1, 1); RELUSTORE(h2, 2); RELUSTORE(h3, 3); \
        u16x8 B4_0 = *(const u16x8*)&s_tile[wv][TSW(c16, kg * 8)];     \
        u16x8 B4_1 = *(const u16x8*)&s_tile[wv][TSW(c16, 32 + kg * 8)];\
        f32x4 cacc = mfma_bf16(AWc2[0], B4_0, *(const f32x4*)&s_bias[80 + kg * 4]); \
        cacc = mfma_bf16(AWc2[1], B4_1, cacc);                         \
        if (kg == 0) {                                                 \
            int si = c * 16 + c16;                                     \
            float r = 1.f / (1.f + __expf(-cacc[0]));                  \
            float g = 1.f / (1.f + __expf(-cacc[1]));                  \
            float b = 1.f / (1.f + __expf(-cacc[2]));                  \
            s_rgbrg[wv][si] = pkh(r, g);                               \
            s_rgbb[wv][si] = (u16)(pkh(b, 0.f) & 0xffffu);             \
        }                                                              \
    }                                                                  \
    float t0 = s_tau[wv][lane];                                        \
    float t1 = s_tau[wv][64 + lane];                                   \
    float x0 = t0, x1 = t1;                                            \
    _Pragma("unroll")                                                  \
    for (int off = 1; off < 64; off <<= 1) {                           \
        float y = __shfl_up(x0, off);                                  \
        if (lane >= off) x0 += y;                                      \
    }                                                                  \
    float tot0 = __shfl(x0, 63);                                       \
    _Pragma("unroll")                                                  \
    for (int off = 1; off < 64; off <<= 1) {                           \
        float y = __shfl_up(x1, off);                                  \
        if (lane >= off) x1 += y;                                      \
    }                                                                  \
    x1 += tot0;                                                        \
    float w0 = __expf(t0 - x0) * (1.f - __expf(-t0));                  \
    float w1s = __expf(t1 - x1) * (1.f - __expf(-t1));                 \
    float2 rg0 = uph(s_rgbrg[wv][lane]);                               \
    float2 rg1 = uph(s_rgbrg[wv][64 + lane]);                          \
    float bb0 = uph((u32)s_rgbb[wv][lane]).x;                          \
    float bb1 = uph((u32)s_rgbb[wv][64 + lane]).x;                     \
    float v0 = w0 * rg0.x + w1s * rg1.x;                               \
    float v1 = w0 * rg0.y + w1s * rg1.y;                               \
    float v2 = w0 * bb0 + w1s * bb1;                                   \
    float v3 = w0 + w1s;                                               \
    _Pragma("unroll")                                                  \
    for (int off = 32; off; off >>= 1) {                               \
        v0 += __shfl_xor(v0, off);                                     \
        v1 += __shfl_xor(v1, off);                                     \
        v2 += __shfl_xor(v2, off);                                     \
        v3 += __shfl_xor(v3, off);                                     \
    }                                                                  \
    if (lane == 0) {                                                   \
        float bg = bg_color[0];                                        \
        out[ray * 3 + 0] = v0 + (1.f - v3) * bg;                       \
        out[ray * 3 + 1] = v1 + (1.f - v3) * bg;                       \
        out[ray * 3 + 2] = v2 + (1.f - v3) * bg;                       \
    }

// ---- HOT kernel: channel-last bf16 grid gather ONLY (clean regalloc) ----
__global__ __launch_bounds__(256)
void nerf_mfma_grid(const float* __restrict__ rays_o,
                    const float* __restrict__ rays_d,
                    const float* __restrict__ bg_color,
                    const float* __restrict__ plane01,
                    const float* __restrict__ plane02,
                    const float* __restrict__ plane12,
                    const float* __restrict__ b1, const float* __restrict__ b2,
                    const float* __restrict__ bc2,
                    const float* __restrict__ aabb,
                    float* __restrict__ out,
                    const u16* __restrict__ wsb,
                    const u16* __restrict__ wsg)
{
    const char* gby = (const char*)wsg;
    KERNEL_BODY(
        u32 o0  = vidx * 64u + (u32)(kg * 16);
        u32 oy  = o0 + 4096u;
        u32 ox  = o0 + 262144u;
        u32 oxy = o0 + 266240u;
        u32x4 q00 = *(const u32x4*)(gby + o0);
        u32x4 q01 = *(const u32x4*)(gby + o0 + 64);
        u32x4 q10 = *(const u32x4*)(gby + oy);
        u32x4 q11 = *(const u32x4*)(gby + oy + 64);
        u32x4 q20 = *(const u32x4*)(gby + ox);
        u32x4 q21 = *(const u32x4*)(gby + ox + 64);
        u32x4 q30 = *(const u32x4*)(gby + oxy);
        u32x4 q31 = *(const u32x4*)(gby + oxy + 64);
        f32x2 p0, p1, p2, p3;
        p0[0] = p0[1] = 0.f; p1 = p0; p2 = p0; p3 = p0;
        CORNER(q00, w0v[0]); CORNER(q01, w0v[1]);
        CORNER(q10, w1v[0]); CORNER(q11, w1v[1]);
        CORNER(q20, w2v[0]); CORNER(q21, w2v[1]);
        CORNER(q30, w3v[0]); CORNER(q31, w3v[1]);
        a1v[0] = pk2bf(p0[0], p0[1]);
        a1v[1] = pk2bf(p1[0], p1[1]);
        a1v[2] = pk2bf(p2[0], p2[1]);
        a1v[3] = pk2bf(p3[0], p3[1]);
    )
}

// ---- fallback kernel: planar f32 gather (only used if ws too small) ----
__global__ __launch_bounds__(256)
void nerf_mfma_planar(const float* __restrict__ rays_o,
                      const float* __restrict__ rays_d,
                      const float* __restrict__ bg_color,
                      const float* __restrict__ plane01,
                      const float* __restrict__ plane02,
                      const float* __restrict__ plane12,
                      const float* __restrict__ b1, const float* __restrict__ b2,
                      const float* __restrict__ bc2,
                      const float* __restrict__ aabb,
                      float* __restrict__ out,
                      const u16* __restrict__ wsb,
                      const float* __restrict__ features)
{
    const char* fby  = (const char*)features;
    const char* fby2 = fby + 16384;
    KERNEL_BODY(
        u32 chb = vidx * 4u + (u32)(kg * 8) * 1048576u;
        _Pragma("unroll")
        for (int jj = 0; jj < 4; ++jj) {
            float vv[2];
            _Pragma("unroll")
            for (int h = 0; h < 2; ++h) {
                u32 off = chb + (u32)(jj * 2 + h) * 1048576u;
                f32x2 q0 = *(const f32x2u*)(fby + off);
                f32x2 q1 = *(const f32x2u*)(fby + off + 256);
                f32x2 q2 = *(const f32x2u*)(fby2 + off);
                f32x2 q3 = *(const f32x2u*)(fby2 + off + 256);
                f32x2 acc = q0 * w0v;
                acc = __builtin_elementwise_fma(q1, w1v, acc);
                acc = __builtin_elementwise_fma(q2, w2v, acc);
                acc = __builtin_elementwise_fma(q3, w3v, acc);
                vv[h] = acc[0] + acc[1];
            }
            a1v[jj] = pk2bf(vv[0], vv[1]);
        }
    )
}

extern "C" void kernel_launch(void* const* d_in, const int* in_sizes, int n_in,
                              void* d_out, int out_size, void* d_ws, size_t ws_size,
                              hipStream_t stream) {
    const float* rays_o  = (const float*)d_in[0];
    const float* rays_d  = (const float*)d_in[1];
    const float* bg      = (const float*)d_in[2];
    const float* p01     = (const float*)d_in[3];
    const float* p02     = (const float*)d_in[4];
    const float* p12     = (const float*)d_in[5];
    const float* feats   = (const float*)d_in[6];
    const float* w1      = (const float*)d_in[7];
    const float* b1      = (const float*)d_in[8];
    const float* w2      = (const float*)d_in[9];
    const float* b2      = (const float*)d_in[10];
    const float* wc1     = (const float*)d_in[11];
    const float* bc1     = (const float*)d_in[12];
    const float* wc2     = (const float*)d_in[13];
    const float* bc2     = (const float*)d_in[14];
    const float* aabb    = (const float*)d_in[15];
    float* out = (float*)d_out;

    const int use_grid = (ws_size >= (size_t)GRID_BYTES + 12288) ? 1 : 0;
    u16* wsg = (u16*)d_ws;
    u16* wsb = use_grid ? (u16*)((char*)d_ws + GRID_BYTES) : (u16*)d_ws;

    prep_weights<<<24, 256, 0, stream>>>(w1, wc1, w2, wc2, bc1, wsb);
    if (use_grid) {
        prep_grid<<<1024, 256, 0, stream>>>(feats, wsg);
        nerf_mfma_grid<<<NRAYS / 4, 256, 0, stream>>>(
            rays_o, rays_d, bg, p01, p02, p12, b1, b2, bc2, aabb, out, wsb, wsg);
    } else {
        nerf_mfma_planar<<<NRAYS / 4, 256, 0, stream>>>(
            rays_o, rays_d, bg, p01, p02, p12, b1, b2, bc2, aabb, out, wsb, feats);
    }
}